// Round 3
// baseline (534.353 us; speedup 1.0000x reference)
//
#include <hip/hip_runtime.h>
#include <hip/hip_bf16.h>

typedef __attribute__((ext_vector_type(8))) short bf16x8;
typedef __attribute__((ext_vector_type(8))) unsigned short u16x8;
typedef __attribute__((ext_vector_type(4))) float f32x4;

#define SEQ   8192
#define DEM   256
#define SCALE 0.0625f   // 1/sqrt(256)
#define CHUNK 512
#define NTASKS 272      // sum over 32 qtiles (256 rows) of (q>>1)+1

#define GLOAD_LDS16(g, l) \
  __builtin_amdgcn_global_load_lds((const __attribute__((address_space(1))) void*)(g), \
                                   (__attribute__((address_space(3))) void*)(l), 16, 0, 0)

static __device__ __forceinline__ unsigned short f2bf(float f) {
  union { float f; unsigned int u; } v; v.f = f;
  return (unsigned short)((v.u + 0x7fffu + ((v.u >> 16) & 1u)) >> 16);
}
static __device__ __forceinline__ float bf2f(unsigned short h) {
  union { unsigned int u; float f; } v; v.u = ((unsigned int)h) << 16;
  return v.f;
}

// ---- projections: qb[s][d] = sum_e x[s][e] Wq[d][e]; kb likewise; vtb[d][s] = sum_e x[s][e] Wv[d][e]
__global__ __launch_bounds__(256) void proj_kernel(
    const float* __restrict__ x,  const float* __restrict__ Wq,
    const float* __restrict__ Wk, const float* __restrict__ Wv,
    unsigned short* __restrict__ qb, unsigned short* __restrict__ kb,
    unsigned short* __restrict__ vtb)
{
  const int m0 = blockIdx.x * 128;
  const int n0 = blockIdx.y * 128;
  const int which = blockIdx.z;
  const float* __restrict__ W = (which == 0) ? Wq : (which == 1) ? Wk : Wv;

  __shared__ unsigned short As[128 * 64];
  __shared__ unsigned short Bs[128 * 64];

  const int tid  = threadIdx.x;
  const int wave = tid >> 6, lane = tid & 63;
  const int wm = wave >> 1, wn = wave & 1;
  const int lr = lane & 15, lg = lane >> 4;

  f32x4 acc[4][4];
  #pragma unroll
  for (int i = 0; i < 4; i++)
    #pragma unroll
    for (int j = 0; j < 4; j++) acc[i][j] = (f32x4){0.f, 0.f, 0.f, 0.f};

  for (int k0 = 0; k0 < DEM; k0 += 64) {
    __syncthreads();
    #pragma unroll
    for (int p = 0; p < 8; p++) {
      int c   = p * 256 + tid;
      int row = c >> 4;
      int col = (c & 15) << 2;
      float4 fA = *reinterpret_cast<const float4*>(&x[(m0 + row) * DEM + k0 + col]);
      float4 fB = *reinterpret_cast<const float4*>(&W[(n0 + row) * DEM + k0 + col]);
      uint2 hA, hB;
      hA.x = f2bf(fA.x) | ((unsigned)f2bf(fA.y) << 16);
      hA.y = f2bf(fA.z) | ((unsigned)f2bf(fA.w) << 16);
      hB.x = f2bf(fB.x) | ((unsigned)f2bf(fB.y) << 16);
      hB.y = f2bf(fB.z) | ((unsigned)f2bf(fB.w) << 16);
      int byte = (row * 128 + (col << 1)) ^ ((row & 7) << 4);
      *reinterpret_cast<uint2*>(reinterpret_cast<char*>(As) + byte) = hA;
      *reinterpret_cast<uint2*>(reinterpret_cast<char*>(Bs) + byte) = hB;
    }
    __syncthreads();

    #pragma unroll
    for (int ks = 0; ks < 2; ks++) {
      bf16x8 a[4], b[4];
      #pragma unroll
      for (int mt = 0; mt < 4; mt++) {
        int row  = wm * 64 + mt * 16 + lr;
        int byte = (row * 128 + ks * 64 + lg * 16) ^ ((row & 7) << 4);
        a[mt] = *reinterpret_cast<const bf16x8*>(reinterpret_cast<const char*>(As) + byte);
      }
      #pragma unroll
      for (int nt = 0; nt < 4; nt++) {
        int row  = wn * 64 + nt * 16 + lr;
        int byte = (row * 128 + ks * 64 + lg * 16) ^ ((row & 7) << 4);
        b[nt] = *reinterpret_cast<const bf16x8*>(reinterpret_cast<const char*>(Bs) + byte);
      }
      #pragma unroll
      for (int mt = 0; mt < 4; mt++)
        #pragma unroll
        for (int nt = 0; nt < 4; nt++)
          acc[mt][nt] = __builtin_amdgcn_mfma_f32_16x16x32_bf16(a[mt], b[nt], acc[mt][nt], 0, 0, 0);
    }
  }

  #pragma unroll
  for (int mt = 0; mt < 4; mt++)
    #pragma unroll
    for (int nt = 0; nt < 4; nt++)
      #pragma unroll
      for (int r = 0; r < 4; r++) {
        int row = m0 + wm * 64 + mt * 16 + lg * 4 + r;
        int col = n0 + wn * 64 + nt * 16 + lr;
        unsigned short h = f2bf(acc[mt][nt][r]);
        if (which == 0)      qb[row * DEM + col]  = h;
        else if (which == 1) kb[row * DEM + col]  = h;
        else                 vtb[(size_t)col * SEQ + row] = h;
      }
}

// ---- attention: block = (qtile of 256 rows, kv chunk <=512). 8 waves x 32 q-rows.
// K double-buffered LDS (2x32KB) + V single (32KB) staged via global_load_lds
// (pre-swizzled global source, swizzled ds_read). 2-phase pipeline, 2 barriers/iter.
__global__ __launch_bounds__(512, 2) void attn_kernel(
    const unsigned short* __restrict__ qb, const unsigned short* __restrict__ kb,
    const unsigned short* __restrict__ vtb,
    unsigned short* __restrict__ pOb, float* __restrict__ ml)
{
  __shared__ char lds[131072];
  char* Ks = lds;               // 2 x 32KB K tiles [64 rows x 512B], swizzled
  char* Vs = lds + 65536;       // 32KB Vt tile [256 rows x 128B], swizzled
  char* Ps = lds + 98304;       // 8 waves x 4KB P [32 rows x 128B], swizzled

  const int t = blockIdx.x;
  int q = 0, s = 0;
  for (;;) { int n = (q >> 1) + 1; if (t < s + n) break; s += n; ++q; }
  const int c = t - s;
  const int kv_lo = c * CHUNK;
  const int kv_hi_blk = min(kv_lo + CHUNK, (q + 1) * 256);

  const int tid = threadIdx.x;
  const int wave = tid >> 6, lane = tid & 63;
  const int lr = lane & 15, lg = lane >> 4;
  const int qrow = q * 256 + wave * 32;
  const int kv_hi_w = min(kv_hi_blk, ((qrow + 32 + 63) >> 6) << 6);
  const int stage_base = wave * 4096;   // this wave's 4KB share of each 32KB tile

  f32x4 o[2][16];
  #pragma unroll
  for (int mt = 0; mt < 2; mt++)
    #pragma unroll
    for (int d = 0; d < 16; d++) o[mt][d] = (f32x4){0.f, 0.f, 0.f, 0.f};
  float m_run[2][4], l_run[2][4];
  #pragma unroll
  for (int mt = 0; mt < 2; mt++)
    #pragma unroll
    for (int r = 0; r < 4; r++) { m_run[mt][r] = -3.0e38f; l_run[mt][r] = 0.f; }

  // ---- prologue: stage K tile 0
  {
    #pragma unroll
    for (int i = 0; i < 4; i++) {
      int sb = stage_base + i * 1024;
      int sl = sb + lane * 16;
      int row = sl >> 9;
      int inrow = (sl & 511) ^ ((row & 7) << 4);
      GLOAD_LDS16((const char*)kb + (((size_t)(kv_lo + row)) << 9) + inrow, Ks + sb);
    }
  }
  __syncthreads();

  for (int kv0 = kv_lo; kv0 < kv_hi_blk; kv0 += 64) {
    const int cur = ((kv0 - kv_lo) >> 6) & 1;
    // ---- issue async stages: V(t) and K(t+1)
    #pragma unroll
    for (int i = 0; i < 4; i++) {
      int sb = stage_base + i * 1024;
      int sl = sb + lane * 16;
      int row = sl >> 7;
      int inrow = (sl & 127) ^ ((row & 7) << 4);
      GLOAD_LDS16((const char*)vtb + ((size_t)row << 14) + (size_t)(kv0 * 2) + inrow, Vs + sb);
    }
    if (kv0 + 64 < kv_hi_blk) {
      #pragma unroll
      for (int i = 0; i < 4; i++) {
        int sb = stage_base + i * 1024;
        int sl = sb + lane * 16;
        int row = sl >> 9;
        int inrow = (sl & 511) ^ ((row & 7) << 4);
        GLOAD_LDS16((const char*)kb + (((size_t)(kv0 + 64 + row)) << 9) + inrow,
                    Ks + (cur ^ 1) * 32768 + sb);
      }
    }

    const bool act = kv0 < kv_hi_w;
    char* pb = Ps + wave * 4096;
    if (act) {
      const char* kbase = Ks + cur * 32768;
      const bool diag = (kv0 + 63 > qrow);
      #pragma unroll
      for (int mt = 0; mt < 2; mt++) {
        // Q fragments for this 16-row half (L1/L2-hot re-read keeps VGPR low)
        bf16x8 qf[8];
        const unsigned short* qp = qb + (size_t)(qrow + mt * 16 + lr) * DEM + lg * 8;
        #pragma unroll
        for (int ks = 0; ks < 8; ks++) qf[ks] = *reinterpret_cast<const bf16x8*>(qp + ks * 32);
        f32x4 sc[4];
        #pragma unroll
        for (int nt = 0; nt < 4; nt++) sc[nt] = (f32x4){0.f, 0.f, 0.f, 0.f};
        #pragma unroll
        for (int ks = 0; ks < 8; ks++)
          #pragma unroll
          for (int nt = 0; nt < 4; nt++) {
            int krow = nt * 16 + lr;
            int byte = (krow * 512 + ks * 64 + lg * 16) ^ ((krow & 7) << 4);
            bf16x8 kf = *reinterpret_cast<const bf16x8*>(kbase + byte);
            sc[nt] = __builtin_amdgcn_mfma_f32_16x16x32_bf16(qf[ks], kf, sc[nt], 0, 0, 0);
          }
        // ---- online softmax for this half
        #pragma unroll
        for (int r = 0; r < 4; r++) {
          const int row_g = qrow + mt * 16 + lg * 4 + r;
          float sm0 = sc[0][r] * SCALE, sm1 = sc[1][r] * SCALE;
          float sm2 = sc[2][r] * SCALE, sm3 = sc[3][r] * SCALE;
          if (diag) {
            if (kv0 +      lr > row_g) sm0 = -3.0e38f;
            if (kv0 + 16 + lr > row_g) sm1 = -3.0e38f;
            if (kv0 + 32 + lr > row_g) sm2 = -3.0e38f;
            if (kv0 + 48 + lr > row_g) sm3 = -3.0e38f;
          }
          float mx = fmaxf(fmaxf(sm0, sm1), fmaxf(sm2, sm3));
          mx = fmaxf(mx, __shfl_xor(mx, 1));
          mx = fmaxf(mx, __shfl_xor(mx, 2));
          mx = fmaxf(mx, __shfl_xor(mx, 4));
          mx = fmaxf(mx, __shfl_xor(mx, 8));
          const float mnew = fmaxf(m_run[mt][r], mx);
          const float cr = __expf(m_run[mt][r] - mnew);
          const float e0 = __expf(sm0 - mnew), e1 = __expf(sm1 - mnew);
          const float e2 = __expf(sm2 - mnew), e3 = __expf(sm3 - mnew);
          float sum = (e0 + e1) + (e2 + e3);
          sum += __shfl_xor(sum, 1);
          sum += __shfl_xor(sum, 2);
          sum += __shfl_xor(sum, 4);
          sum += __shfl_xor(sum, 8);
          m_run[mt][r] = mnew;
          l_run[mt][r] = l_run[mt][r] * cr + sum;
          const int prow = mt * 16 + lg * 4 + r;
          const int swz = (prow & 7) << 4;
          *reinterpret_cast<unsigned short*>(pb + ((prow * 128 + lr * 2)      ^ swz)) = f2bf(e0);
          *reinterpret_cast<unsigned short*>(pb + ((prow * 128 + 32 + lr * 2) ^ swz)) = f2bf(e1);
          *reinterpret_cast<unsigned short*>(pb + ((prow * 128 + 64 + lr * 2) ^ swz)) = f2bf(e2);
          *reinterpret_cast<unsigned short*>(pb + ((prow * 128 + 96 + lr * 2) ^ swz)) = f2bf(e3);
          #pragma unroll
          for (int d = 0; d < 16; d++) o[mt][d][r] *= cr;
        }
      }
    }
    __syncthreads();   // drains gload_lds (V(t), K(t+1)) + P writes visible to self

    if (act) {
      #pragma unroll
      for (int mt = 0; mt < 2; mt++) {
        const int prow = mt * 16 + lr;
        const int pswz = (prow & 7) << 4;
        bf16x8 pf0 = *reinterpret_cast<const bf16x8*>(pb + ((prow * 128 + lg * 16)      ^ pswz));
        bf16x8 pf1 = *reinterpret_cast<const bf16x8*>(pb + ((prow * 128 + 64 + lg * 16) ^ pswz));
        #pragma unroll
        for (int d = 0; d < 16; d++) {
          const int vrow = d * 16 + lr;
          const int vswz = (vrow & 7) << 4;
          bf16x8 v0 = *reinterpret_cast<const bf16x8*>(Vs + ((vrow * 128 + lg * 16)      ^ vswz));
          bf16x8 v1 = *reinterpret_cast<const bf16x8*>(Vs + ((vrow * 128 + 64 + lg * 16) ^ vswz));
          o[mt][d] = __builtin_amdgcn_mfma_f32_16x16x32_bf16(pf0, v0, o[mt][d], 0, 0, 0);
          o[mt][d] = __builtin_amdgcn_mfma_f32_16x16x32_bf16(pf1, v1, o[mt][d], 0, 0, 0);
        }
      }
    }
    __syncthreads();   // protect Vs / K[cur] before next iter's stages
  }

  // ---- write partials (bf16 O, f32 m/l)
  const size_t obase = ((size_t)t << 16);
  #pragma unroll
  for (int mt = 0; mt < 2; mt++)
    #pragma unroll
    for (int d = 0; d < 16; d++)
      #pragma unroll
      for (int r = 0; r < 4; r++) {
        const int row_l = wave * 32 + mt * 16 + lg * 4 + r;
        pOb[obase + (size_t)row_l * 256 + d * 16 + lr] = f2bf(o[mt][d][r]);
      }
  if (lr == 0) {
    #pragma unroll
    for (int mt = 0; mt < 2; mt++)
      #pragma unroll
      for (int r = 0; r < 4; r++) {
        const int row_l = wave * 32 + mt * 16 + lg * 4 + r;
        ml[(size_t)t * 512 + row_l * 2]     = m_run[mt][r];
        ml[(size_t)t * 512 + row_l * 2 + 1] = l_run[mt][r];
      }
  }
}

// ---- merge partials
__global__ __launch_bounds__(256) void merge_kernel(
    const unsigned short* __restrict__ pOb, const float* __restrict__ ml,
    float* __restrict__ out)
{
  const int tid = threadIdx.x;
  const int row = blockIdx.x * 32 + (tid >> 3);
  const int c0  = (tid & 7) * 32;
  const int q = row >> 8;
  const int h = q >> 1;
  const int n = h + 1;
  const int base = q + h * (h - 1) + (q & 1) * h;
  const int lrow = row & 255;

  float M = -3.0e38f;
  for (int i = 0; i < n; i++)
    M = fmaxf(M, ml[(size_t)(base + i) * 512 + lrow * 2]);

  float L = 0.f;
  float acc[32];
  #pragma unroll
  for (int j = 0; j < 32; j++) acc[j] = 0.f;

  for (int i = 0; i < n; i++) {
    const float mi = ml[(size_t)(base + i) * 512 + lrow * 2];
    const float li = ml[(size_t)(base + i) * 512 + lrow * 2 + 1];
    const float fi = __expf(mi - M);
    L += li * fi;
    const unsigned short* src = pOb + (((size_t)(base + i)) << 16) + (size_t)lrow * 256 + c0;
    #pragma unroll
    for (int v = 0; v < 4; v++) {
      u16x8 u = *reinterpret_cast<const u16x8*>(src + v * 8);
      #pragma unroll
      for (int j = 0; j < 8; j++) acc[v * 8 + j] += bf2f((unsigned short)u[j]) * fi;
    }
  }
  const float inv = 1.f / L;
  #pragma unroll
  for (int v = 0; v < 8; v++) {
    float4 w;
    w.x = acc[v * 4 + 0] * inv; w.y = acc[v * 4 + 1] * inv;
    w.z = acc[v * 4 + 2] * inv; w.w = acc[v * 4 + 3] * inv;
    *reinterpret_cast<float4*>(&out[(size_t)row * 256 + c0 + v * 4]) = w;
  }
}

extern "C" void kernel_launch(void* const* d_in, const int* in_sizes, int n_in,
                              void* d_out, int out_size, void* d_ws, size_t ws_size,
                              hipStream_t stream)
{
  const float* x  = (const float*)d_in[0];
  const float* Wq = (const float*)d_in[1];
  const float* Wk = (const float*)d_in[2];
  const float* Wv = (const float*)d_in[3];

  char* ws = (char*)d_ws;
  unsigned short* qb  = (unsigned short*)ws;                              // 4 MB
  unsigned short* kb  = (unsigned short*)(ws + (size_t)4  * 1024 * 1024); // 4 MB
  unsigned short* vtb = (unsigned short*)(ws + (size_t)8  * 1024 * 1024); // 4 MB
  float*          ml  = (float*)         (ws + (size_t)12 * 1024 * 1024); // 557 KB
  unsigned short* pOb = (unsigned short*)(ws + (size_t)13 * 1024 * 1024); // 34.1 MB

  proj_kernel<<<dim3(64, 2, 3), 256, 0, stream>>>(x, Wq, Wk, Wv, qb, kb, vtb);
  attn_kernel<<<dim3(NTASKS), 512, 0, stream>>>(qb, kb, vtb, pOb, ml);
  merge_kernel<<<dim3(SEQ / 32), 256, 0, stream>>>(pOb, ml, (float*)d_out);
}

// Round 4
// 392.191 us; speedup vs baseline: 1.3625x; 1.3625x over previous
//
#include <hip/hip_runtime.h>
#include <hip/hip_bf16.h>

typedef __attribute__((ext_vector_type(8))) short bf16x8;
typedef __attribute__((ext_vector_type(8))) unsigned short u16x8;
typedef __attribute__((ext_vector_type(4))) float f32x4;

#define SEQ   8192
#define DEM   256
#define CHUNK 512
#define NTASKS 1088     // sum over 128 qtiles (64 rows) of (q>>3)+1

static __device__ __forceinline__ unsigned short f2bf(float f) {
  union { float f; unsigned int u; } v; v.f = f;
  return (unsigned short)((v.u + 0x7fffu + ((v.u >> 16) & 1u)) >> 16);
}
static __device__ __forceinline__ float bf2f(unsigned short h) {
  union { unsigned int u; float f; } v; v.u = ((unsigned int)h) << 16;
  return v.f;
}

// ---- projections: qb[s][d] = (1/16)*sum_e x[s][e] Wq[d][e] (scale folded, exact pow2);
//      kb[s][d] = sum_e x[s][e] Wk[d][e]; vtb[d][s] = sum_e x[s][e] Wv[d][e]
__global__ __launch_bounds__(256) void proj_kernel(
    const float* __restrict__ x,  const float* __restrict__ Wq,
    const float* __restrict__ Wk, const float* __restrict__ Wv,
    unsigned short* __restrict__ qb, unsigned short* __restrict__ kb,
    unsigned short* __restrict__ vtb)
{
  const int m0 = blockIdx.x * 128;
  const int n0 = blockIdx.y * 128;
  const int which = blockIdx.z;
  const float* __restrict__ W = (which == 0) ? Wq : (which == 1) ? Wk : Wv;

  __shared__ unsigned short As[128 * 64];
  __shared__ unsigned short Bs[128 * 64];

  const int tid  = threadIdx.x;
  const int wave = tid >> 6, lane = tid & 63;
  const int wm = wave >> 1, wn = wave & 1;
  const int lr = lane & 15, lg = lane >> 4;

  f32x4 acc[4][4];
  #pragma unroll
  for (int i = 0; i < 4; i++)
    #pragma unroll
    for (int j = 0; j < 4; j++) acc[i][j] = (f32x4){0.f, 0.f, 0.f, 0.f};

  for (int k0 = 0; k0 < DEM; k0 += 64) {
    __syncthreads();
    #pragma unroll
    for (int p = 0; p < 8; p++) {
      int c   = p * 256 + tid;
      int row = c >> 4;
      int col = (c & 15) << 2;
      float4 fA = *reinterpret_cast<const float4*>(&x[(m0 + row) * DEM + k0 + col]);
      float4 fB = *reinterpret_cast<const float4*>(&W[(n0 + row) * DEM + k0 + col]);
      uint2 hA, hB;
      hA.x = f2bf(fA.x) | ((unsigned)f2bf(fA.y) << 16);
      hA.y = f2bf(fA.z) | ((unsigned)f2bf(fA.w) << 16);
      hB.x = f2bf(fB.x) | ((unsigned)f2bf(fB.y) << 16);
      hB.y = f2bf(fB.z) | ((unsigned)f2bf(fB.w) << 16);
      int byte = (row * 128 + (col << 1)) ^ ((row & 7) << 4);
      *reinterpret_cast<uint2*>(reinterpret_cast<char*>(As) + byte) = hA;
      *reinterpret_cast<uint2*>(reinterpret_cast<char*>(Bs) + byte) = hB;
    }
    __syncthreads();

    #pragma unroll
    for (int ks = 0; ks < 2; ks++) {
      bf16x8 a[4], b[4];
      #pragma unroll
      for (int mt = 0; mt < 4; mt++) {
        int row  = wm * 64 + mt * 16 + lr;
        int byte = (row * 128 + ks * 64 + lg * 16) ^ ((row & 7) << 4);
        a[mt] = *reinterpret_cast<const bf16x8*>(reinterpret_cast<const char*>(As) + byte);
      }
      #pragma unroll
      for (int nt = 0; nt < 4; nt++) {
        int row  = wn * 64 + nt * 16 + lr;
        int byte = (row * 128 + ks * 64 + lg * 16) ^ ((row & 7) << 4);
        b[nt] = *reinterpret_cast<const bf16x8*>(reinterpret_cast<const char*>(Bs) + byte);
      }
      #pragma unroll
      for (int mt = 0; mt < 4; mt++)
        #pragma unroll
        for (int nt = 0; nt < 4; nt++)
          acc[mt][nt] = __builtin_amdgcn_mfma_f32_16x16x32_bf16(a[mt], b[nt], acc[mt][nt], 0, 0, 0);
    }
  }

  const float osc = (which == 0) ? 0.0625f : 1.0f;   // fold 1/sqrt(256) into Q, exact pow2
  #pragma unroll
  for (int mt = 0; mt < 4; mt++)
    #pragma unroll
    for (int nt = 0; nt < 4; nt++)
      #pragma unroll
      for (int r = 0; r < 4; r++) {
        int row = m0 + wm * 64 + mt * 16 + lg * 4 + r;
        int col = n0 + wn * 64 + nt * 16 + lr;
        unsigned short h = f2bf(acc[mt][nt][r] * osc);
        if (which == 0)      qb[row * DEM + col]  = h;
        else if (which == 1) kb[row * DEM + col]  = h;
        else                 vtb[(size_t)col * SEQ + row] = h;
      }
}

// ---- one KV step of NT*16 keys for a 16-q-row wave fragment
template <int NT>
static __device__ __forceinline__ void kv_tile(
    const unsigned short* __restrict__ kb,
    const unsigned short* __restrict__ vtb,
    const bf16x8 (&qf)[8], char* __restrict__ pb,
    f32x4 (&o)[16], float (&m_run)[4], float (&l_run)[4],
    const int kv0, const int qrow, const int lr, const int lg)
{
  constexpr int ROWB = NT * 32;    // P-tile row stride in bytes
  f32x4 sc[NT];
  #pragma unroll
  for (int nt = 0; nt < NT; nt++) sc[nt] = (f32x4){0.f, 0.f, 0.f, 0.f};

  const unsigned short* kp = kb + (size_t)(kv0 + lr) * DEM + lg * 8;
  #pragma unroll
  for (int ks = 0; ks < 8; ks++)
    #pragma unroll
    for (int nt = 0; nt < NT; nt++) {
      bf16x8 kf = *reinterpret_cast<const bf16x8*>(kp + nt * 16 * DEM + ks * 32);
      sc[nt] = __builtin_amdgcn_mfma_f32_16x16x32_bf16(qf[ks], kf, sc[nt], 0, 0, 0);
    }

  const bool diag = (kv0 + NT * 16 - 1 > qrow);
  #pragma unroll
  for (int r = 0; r < 4; r++) {
    const int row_g = qrow + lg * 4 + r;
    float sm[NT];
    #pragma unroll
    for (int j = 0; j < NT; j++) {
      sm[j] = sc[j][r];
      if (diag && (kv0 + j * 16 + lr > row_g)) sm[j] = -3.0e38f;
    }
    float mx = sm[0];
    #pragma unroll
    for (int j = 1; j < NT; j++) mx = fmaxf(mx, sm[j]);
    mx = fmaxf(mx, __shfl_xor(mx, 1));
    mx = fmaxf(mx, __shfl_xor(mx, 2));
    mx = fmaxf(mx, __shfl_xor(mx, 4));
    mx = fmaxf(mx, __shfl_xor(mx, 8));
    const float mnew = fmaxf(m_run[r], mx);
    const float cr = __expf(m_run[r] - mnew);
    float e[NT], sum = 0.f;
    #pragma unroll
    for (int j = 0; j < NT; j++) { e[j] = __expf(sm[j] - mnew); sum += e[j]; }
    sum += __shfl_xor(sum, 1);
    sum += __shfl_xor(sum, 2);
    sum += __shfl_xor(sum, 4);
    sum += __shfl_xor(sum, 8);
    m_run[r] = mnew;
    l_run[r] = l_run[r] * cr + sum;
    const int prow = lg * 4 + r;
    const int swz = (prow & 7) << 4;
    #pragma unroll
    for (int j = 0; j < NT; j++)
      *reinterpret_cast<unsigned short*>(pb + ((prow * ROWB + j * 32 + lr * 2) ^ swz)) = f2bf(e[j]);
    #pragma unroll
    for (int d = 0; d < 16; d++) o[d][r] *= cr;
  }

  // PV: o[q][dcol] += P[q][kv] * Vt[dcol][kv]
  const int pswz = (lr & 7) << 4;
  bf16x8 pf[NT / 2];
  #pragma unroll
  for (int i = 0; i < NT / 2; i++)
    pf[i] = *reinterpret_cast<const bf16x8*>(pb + ((lr * ROWB + i * 64 + lg * 16) ^ pswz));
  #pragma unroll
  for (int d = 0; d < 16; d++) {
    const unsigned short* vp = vtb + (size_t)(d * 16 + lr) * SEQ + kv0 + lg * 8;
    #pragma unroll
    for (int i = 0; i < NT / 2; i++) {
      bf16x8 vf = *reinterpret_cast<const bf16x8*>(vp + i * 32);
      o[d] = __builtin_amdgcn_mfma_f32_16x16x32_bf16(pf[i], vf, o[d], 0, 0, 0);
    }
  }
}

// ---- attention: task = (qtile of 64 rows, kv chunk <=512). 4 waves x 16 q-rows.
// No barriers; K/V read directly from global (L2-hot). 128-kv main steps + 64 tail.
__global__ __launch_bounds__(256, 2) void attn_kernel(
    const unsigned short* __restrict__ qb, const unsigned short* __restrict__ kb,
    const unsigned short* __restrict__ vtb,
    unsigned short* __restrict__ pOb, float* __restrict__ ml)
{
  __shared__ char Ps[4][4096];
  const int t = NTASKS - 1 - (int)blockIdx.x;   // largest tasks first
  int q = 0, s = 0;
  for (;;) { int n = (q >> 3) + 1; if (t < s + n) break; s += n; ++q; }
  const int c = t - s;
  const int kv_lo = c * CHUNK;
  const int kv_hi_blk = min(kv_lo + CHUNK, (q + 1) * 64);

  const int tid = threadIdx.x;
  const int wave = tid >> 6, lane = tid & 63;
  const int lr = lane & 15, lg = lane >> 4;
  const int qrow = q * 64 + wave * 16;
  const int kv_hi_w = min(kv_hi_blk, ((qrow + 16 + 63) >> 6) << 6);
  char* pb = Ps[wave];

  bf16x8 qf[8];
  #pragma unroll
  for (int ks = 0; ks < 8; ks++)
    qf[ks] = *reinterpret_cast<const bf16x8*>(&qb[(size_t)(qrow + lr) * DEM + ks * 32 + lg * 8]);

  f32x4 o[16];
  #pragma unroll
  for (int d = 0; d < 16; d++) o[d] = (f32x4){0.f, 0.f, 0.f, 0.f};
  float m_run[4], l_run[4];
  #pragma unroll
  for (int r = 0; r < 4; r++) { m_run[r] = -3.0e38f; l_run[r] = 0.f; }

  int kv0 = kv_lo;
  while (kv0 + 128 <= kv_hi_w) {
    kv_tile<8>(kb, vtb, qf, pb, o, m_run, l_run, kv0, qrow, lr, lg);
    kv0 += 128;
  }
  if (kv0 < kv_hi_w) {
    kv_tile<4>(kb, vtb, qf, pb, o, m_run, l_run, kv0, qrow, lr, lg);
  }

  // ---- write partials (bf16 O, f32 m/l)
  const size_t obase = (size_t)t * (64 * 256);
  #pragma unroll
  for (int d = 0; d < 16; d++)
    #pragma unroll
    for (int r = 0; r < 4; r++) {
      const int row_l = wave * 16 + lg * 4 + r;
      pOb[obase + (size_t)row_l * 256 + d * 16 + lr] = f2bf(o[d][r]);
    }
  if (lr == 0) {
    #pragma unroll
    for (int r = 0; r < 4; r++) {
      const int row_l = wave * 16 + lg * 4 + r;
      ml[(size_t)t * 128 + row_l * 2]     = m_run[r];
      ml[(size_t)t * 128 + row_l * 2 + 1] = l_run[r];
    }
  }
}

// ---- merge partials
__global__ __launch_bounds__(256) void merge_kernel(
    const unsigned short* __restrict__ pOb, const float* __restrict__ ml,
    float* __restrict__ out)
{
  const int tid = threadIdx.x;
  const int row = blockIdx.x * 32 + (tid >> 3);
  const int c0  = (tid & 7) * 32;
  const int q = row >> 6;              // 64-row qtile
  const int a = q >> 3, b = q & 7;
  const int n = a + 1;                 // chunks for this qtile
  const int base = q + 4 * a * (a - 1) + b * a;
  const int lrow = row & 63;

  float M = -3.0e38f;
  for (int i = 0; i < n; i++)
    M = fmaxf(M, ml[(size_t)(base + i) * 128 + lrow * 2]);

  float L = 0.f;
  float acc[32];
  #pragma unroll
  for (int j = 0; j < 32; j++) acc[j] = 0.f;

  for (int i = 0; i < n; i++) {
    const float mi = ml[(size_t)(base + i) * 128 + lrow * 2];
    const float li = ml[(size_t)(base + i) * 128 + lrow * 2 + 1];
    const float fi = __expf(mi - M);
    L += li * fi;
    const unsigned short* src = pOb + (size_t)(base + i) * (64 * 256) + (size_t)lrow * 256 + c0;
    #pragma unroll
    for (int v = 0; v < 4; v++) {
      u16x8 u = *reinterpret_cast<const u16x8*>(src + v * 8);
      #pragma unroll
      for (int j = 0; j < 8; j++) acc[v * 8 + j] += bf2f((unsigned short)u[j]) * fi;
    }
  }
  const float inv = 1.f / L;
  #pragma unroll
  for (int v = 0; v < 8; v++) {
    float4 w;
    w.x = acc[v * 4 + 0] * inv; w.y = acc[v * 4 + 1] * inv;
    w.z = acc[v * 4 + 2] * inv; w.w = acc[v * 4 + 3] * inv;
    *reinterpret_cast<float4*>(&out[(size_t)row * 256 + c0 + v * 4]) = w;
  }
}

extern "C" void kernel_launch(void* const* d_in, const int* in_sizes, int n_in,
                              void* d_out, int out_size, void* d_ws, size_t ws_size,
                              hipStream_t stream)
{
  const float* x  = (const float*)d_in[0];
  const float* Wq = (const float*)d_in[1];
  const float* Wk = (const float*)d_in[2];
  const float* Wv = (const float*)d_in[3];

  char* ws = (char*)d_ws;
  unsigned short* qb  = (unsigned short*)ws;                              // 4 MB
  unsigned short* kb  = (unsigned short*)(ws + (size_t)4  * 1024 * 1024); // 4 MB
  unsigned short* vtb = (unsigned short*)(ws + (size_t)8  * 1024 * 1024); // 4 MB
  float*          ml  = (float*)         (ws + (size_t)12 * 1024 * 1024); // 557 KB
  unsigned short* pOb = (unsigned short*)(ws + (size_t)13 * 1024 * 1024); // 35.7 MB

  proj_kernel<<<dim3(64, 2, 3), 256, 0, stream>>>(x, Wq, Wk, Wv, qb, kb, vtb);
  attn_kernel<<<dim3(NTASKS), 256, 0, stream>>>(qb, kb, vtb, pOb, ml);
  merge_kernel<<<dim3(SEQ / 32), 256, 0, stream>>>(pOb, ml, (float*)d_out);
}

// Round 5
// 245.524 us; speedup vs baseline: 2.1764x; 1.5974x over previous
//
#include <hip/hip_runtime.h>
#include <hip/hip_bf16.h>

typedef __attribute__((ext_vector_type(8))) short bf16x8;
typedef __attribute__((ext_vector_type(8))) unsigned short u16x8;
typedef __attribute__((ext_vector_type(4))) float f32x4;

#define SEQ   8192
#define DEM   256
#define CHUNK 512
#define NTASKS 1088     // sum over 128 qtiles (64 rows) of (q>>3)+1

#define GLOAD_LDS16(g, l) \
  __builtin_amdgcn_global_load_lds((const __attribute__((address_space(1))) void*)(g), \
                                   (__attribute__((address_space(3))) void*)(l), 16, 0, 0)

static __device__ __forceinline__ unsigned short f2bf(float f) {
  union { float f; unsigned int u; } v; v.f = f;
  return (unsigned short)((v.u + 0x7fffu + ((v.u >> 16) & 1u)) >> 16);
}
static __device__ __forceinline__ float bf2f(unsigned short h) {
  union { unsigned int u; float f; } v; v.u = ((unsigned int)h) << 16;
  return v.f;
}

// ---- projections: qb[s][d] = (1/16)*sum_e x[s][e] Wq[d][e] (scale folded, exact pow2);
//      kb[s][d] = sum_e x[s][e] Wk[d][e]; vtb[d][s] = sum_e x[s][e] Wv[d][e]
__global__ __launch_bounds__(256) void proj_kernel(
    const float* __restrict__ x,  const float* __restrict__ Wq,
    const float* __restrict__ Wk, const float* __restrict__ Wv,
    unsigned short* __restrict__ qb, unsigned short* __restrict__ kb,
    unsigned short* __restrict__ vtb)
{
  const int m0 = blockIdx.x * 128;
  const int n0 = blockIdx.y * 128;
  const int which = blockIdx.z;
  const float* __restrict__ W = (which == 0) ? Wq : (which == 1) ? Wk : Wv;

  __shared__ unsigned short As[128 * 64];
  __shared__ unsigned short Bs[128 * 64];

  const int tid  = threadIdx.x;
  const int wave = tid >> 6, lane = tid & 63;
  const int wm = wave >> 1, wn = wave & 1;
  const int lr = lane & 15, lg = lane >> 4;

  f32x4 acc[4][4];
  #pragma unroll
  for (int i = 0; i < 4; i++)
    #pragma unroll
    for (int j = 0; j < 4; j++) acc[i][j] = (f32x4){0.f, 0.f, 0.f, 0.f};

  for (int k0 = 0; k0 < DEM; k0 += 64) {
    __syncthreads();
    #pragma unroll
    for (int p = 0; p < 8; p++) {
      int c   = p * 256 + tid;
      int row = c >> 4;
      int col = (c & 15) << 2;
      float4 fA = *reinterpret_cast<const float4*>(&x[(m0 + row) * DEM + k0 + col]);
      float4 fB = *reinterpret_cast<const float4*>(&W[(n0 + row) * DEM + k0 + col]);
      uint2 hA, hB;
      hA.x = f2bf(fA.x) | ((unsigned)f2bf(fA.y) << 16);
      hA.y = f2bf(fA.z) | ((unsigned)f2bf(fA.w) << 16);
      hB.x = f2bf(fB.x) | ((unsigned)f2bf(fB.y) << 16);
      hB.y = f2bf(fB.z) | ((unsigned)f2bf(fB.w) << 16);
      int byte = (row * 128 + (col << 1)) ^ ((row & 7) << 4);
      *reinterpret_cast<uint2*>(reinterpret_cast<char*>(As) + byte) = hA;
      *reinterpret_cast<uint2*>(reinterpret_cast<char*>(Bs) + byte) = hB;
    }
    __syncthreads();

    #pragma unroll
    for (int ks = 0; ks < 2; ks++) {
      bf16x8 a[4], b[4];
      #pragma unroll
      for (int mt = 0; mt < 4; mt++) {
        int row  = wm * 64 + mt * 16 + lr;
        int byte = (row * 128 + ks * 64 + lg * 16) ^ ((row & 7) << 4);
        a[mt] = *reinterpret_cast<const bf16x8*>(reinterpret_cast<const char*>(As) + byte);
      }
      #pragma unroll
      for (int nt = 0; nt < 4; nt++) {
        int row  = wn * 64 + nt * 16 + lr;
        int byte = (row * 128 + ks * 64 + lg * 16) ^ ((row & 7) << 4);
        b[nt] = *reinterpret_cast<const bf16x8*>(reinterpret_cast<const char*>(Bs) + byte);
      }
      #pragma unroll
      for (int mt = 0; mt < 4; mt++)
        #pragma unroll
        for (int nt = 0; nt < 4; nt++)
          acc[mt][nt] = __builtin_amdgcn_mfma_f32_16x16x32_bf16(a[mt], b[nt], acc[mt][nt], 0, 0, 0);
    }
  }

  const float osc = (which == 0) ? 0.0625f : 1.0f;   // fold 1/sqrt(256) into Q
  #pragma unroll
  for (int mt = 0; mt < 4; mt++)
    #pragma unroll
    for (int nt = 0; nt < 4; nt++)
      #pragma unroll
      for (int r = 0; r < 4; r++) {
        int row = m0 + wm * 64 + mt * 16 + lg * 4 + r;
        int col = n0 + wn * 64 + nt * 16 + lr;
        unsigned short h = f2bf(acc[mt][nt][r] * osc);
        if (which == 0)      qb[row * DEM + col]  = h;
        else if (which == 1) kb[row * DEM + col]  = h;
        else                 vtb[(size_t)col * SEQ + row] = h;
      }
}

// ---- attention: task = (qtile of 64 rows, kv chunk <=512). 4 waves x 16 q-rows.
// K staged in LDS (double-buffered, global_load_lds w16, 2-phase pipeline, 1 barrier/step).
// V/Q fragments via explicit early register batches (T14 issue-early/use-late).
__global__ __launch_bounds__(256, 2) void attn_kernel(
    const unsigned short* __restrict__ qb, const unsigned short* __restrict__ kb,
    const unsigned short* __restrict__ vtb,
    unsigned short* __restrict__ pOb, float* __restrict__ ml)
{
  __shared__ char lds[73728];
  char* Ks = lds;             // 2 x 32KB K tiles [64 rows x 512B], swizzled
  char* Ps = lds + 65536;     // 4 waves x 2KB P [16 rows x 128B], swizzled

  const int t = NTASKS - 1 - (int)blockIdx.x;   // largest tasks first
  int q = 0, s = 0;
  for (;;) { int n = (q >> 3) + 1; if (t < s + n) break; s += n; ++q; }
  const int c = t - s;
  const int kv_lo = c * CHUNK;
  const int kv_hi_blk = min(kv_lo + CHUNK, (q + 1) * 64);

  const int tid = threadIdx.x;
  const int wave = tid >> 6, lane = tid & 63;
  const int lr = lane & 15, lg = lane >> 4;
  const int qrow = q * 64 + wave * 16;
  const int kv_hi_w = min(kv_hi_blk, ((qrow + 16 + 63) >> 6) << 6);
  char* pb = Ps + wave * 2048;

  f32x4 o[16];
  #pragma unroll
  for (int d = 0; d < 16; d++) o[d] = (f32x4){0.f, 0.f, 0.f, 0.f};
  float m_run[4], l_run[4];
  #pragma unroll
  for (int r = 0; r < 4; r++) { m_run[r] = -3.0e38f; l_run[r] = 0.f; }

  // prologue: stage K tile 0 into buf 0
  #pragma unroll
  for (int i = 0; i < 8; i++) {
    int sl = i * 4096 + tid * 16;
    int row = sl >> 9;
    int inrow = (sl & 511) ^ ((row & 7) << 4);
    GLOAD_LDS16((const char*)kb + (((size_t)(kv_lo + row)) << 9) + inrow,
                Ks + i * 4096 + (wave << 10));
  }
  __syncthreads();

  const int nsteps = (kv_hi_blk - kv_lo) >> 6;
  for (int st = 0; st < nsteps; st++) {
    const int kv0 = kv_lo + (st << 6);
    const int buf = st & 1;
    // ---- issue async stage of K(t+1) into buf^1 (no VGPR cost)
    if (st + 1 < nsteps) {
      #pragma unroll
      for (int i = 0; i < 8; i++) {
        int sl = i * 4096 + tid * 16;
        int row = sl >> 9;
        int inrow = (sl & 511) ^ ((row & 7) << 4);
        GLOAD_LDS16((const char*)kb + (((size_t)(kv0 + 64 + row)) << 9) + inrow,
                    Ks + (buf ^ 1) * 32768 + i * 4096 + (wave << 10));
      }
    }

    const bool act = kv0 < kv_hi_w;
    if (act) {
      // ---- early-issue register batches: Q fragments + V first-half (T14)
      bf16x8 qf[8], va[16], vb[16];
      const unsigned short* qp = qb + (size_t)(qrow + lr) * DEM + lg * 8;
      #pragma unroll
      for (int ks = 0; ks < 8; ks++) qf[ks] = *reinterpret_cast<const bf16x8*>(qp + ks * 32);
      #pragma unroll
      for (int d = 0; d < 16; d++)
        va[d] = *reinterpret_cast<const bf16x8*>(vtb + (size_t)(d * 16 + lr) * SEQ + kv0 + lg * 8);

      // ---- QK^T from LDS K
      f32x4 sc[4];
      #pragma unroll
      for (int nt = 0; nt < 4; nt++) sc[nt] = (f32x4){0.f, 0.f, 0.f, 0.f};
      const char* kbase = Ks + buf * 32768;
      #pragma unroll
      for (int ks = 0; ks < 8; ks++)
        #pragma unroll
        for (int nt = 0; nt < 4; nt++) {
          int krow = nt * 16 + lr;
          int byte = (krow * 512 + ks * 64 + lg * 16) ^ ((krow & 7) << 4);
          bf16x8 kf = *reinterpret_cast<const bf16x8*>(kbase + byte);
          sc[nt] = __builtin_amdgcn_mfma_f32_16x16x32_bf16(qf[ks], kf, sc[nt], 0, 0, 0);
        }

      // ---- issue V second-half while softmax runs
      #pragma unroll
      for (int d = 0; d < 16; d++)
        vb[d] = *reinterpret_cast<const bf16x8*>(vtb + (size_t)(d * 16 + lr) * SEQ + kv0 + 32 + lg * 8);

      // ---- online softmax (row r in 16-lane group; q-row = qrow + lg*4 + r)
      const bool diag = (kv0 + 63 > qrow);
      #pragma unroll
      for (int r = 0; r < 4; r++) {
        const int row_g = qrow + lg * 4 + r;
        float sm[4];
        #pragma unroll
        for (int j = 0; j < 4; j++) {
          sm[j] = sc[j][r];
          if (diag && (kv0 + j * 16 + lr > row_g)) sm[j] = -3.0e38f;
        }
        float mx = fmaxf(fmaxf(sm[0], sm[1]), fmaxf(sm[2], sm[3]));
        mx = fmaxf(mx, __shfl_xor(mx, 1));
        mx = fmaxf(mx, __shfl_xor(mx, 2));
        mx = fmaxf(mx, __shfl_xor(mx, 4));
        mx = fmaxf(mx, __shfl_xor(mx, 8));
        const float mnew = fmaxf(m_run[r], mx);
        const float cr = __expf(m_run[r] - mnew);
        float e[4], sum = 0.f;
        #pragma unroll
        for (int j = 0; j < 4; j++) { e[j] = __expf(sm[j] - mnew); sum += e[j]; }
        sum += __shfl_xor(sum, 1);
        sum += __shfl_xor(sum, 2);
        sum += __shfl_xor(sum, 4);
        sum += __shfl_xor(sum, 8);
        m_run[r] = mnew;
        l_run[r] = l_run[r] * cr + sum;
        const int prow = lg * 4 + r;
        const int swz = (prow & 7) << 4;
        #pragma unroll
        for (int j = 0; j < 4; j++)
          *reinterpret_cast<unsigned short*>(pb + ((prow * 128 + j * 32 + lr * 2) ^ swz)) = f2bf(e[j]);
        #pragma unroll
        for (int d = 0; d < 16; d++) o[d][r] *= cr;
      }

      // ---- PV from P-LDS + prefetched V registers
      const int pswz = (lr & 7) << 4;
      bf16x8 pf0 = *reinterpret_cast<const bf16x8*>(pb + ((lr * 128 + lg * 16)      ^ pswz));
      bf16x8 pf1 = *reinterpret_cast<const bf16x8*>(pb + ((lr * 128 + 64 + lg * 16) ^ pswz));
      #pragma unroll
      for (int d = 0; d < 16; d++) {
        o[d] = __builtin_amdgcn_mfma_f32_16x16x32_bf16(pf0, va[d], o[d], 0, 0, 0);
        o[d] = __builtin_amdgcn_mfma_f32_16x16x32_bf16(pf1, vb[d], o[d], 0, 0, 0);
      }
    }
    __syncthreads();   // drains stage(t+1); separates K buf reuse
  }

  // ---- write partials (bf16 O, f32 m/l)
  const size_t obase = (size_t)t * (64 * 256);
  #pragma unroll
  for (int d = 0; d < 16; d++)
    #pragma unroll
    for (int r = 0; r < 4; r++) {
      const int row_l = wave * 16 + lg * 4 + r;
      pOb[obase + (size_t)row_l * 256 + d * 16 + lr] = f2bf(o[d][r]);
    }
  if (lr == 0) {
    #pragma unroll
    for (int r = 0; r < 4; r++) {
      const int row_l = wave * 16 + lg * 4 + r;
      ml[(size_t)t * 128 + row_l * 2]     = m_run[r];
      ml[(size_t)t * 128 + row_l * 2 + 1] = l_run[r];
    }
  }
}

// ---- merge partials
__global__ __launch_bounds__(256) void merge_kernel(
    const unsigned short* __restrict__ pOb, const float* __restrict__ ml,
    float* __restrict__ out)
{
  const int tid = threadIdx.x;
  const int row = blockIdx.x * 32 + (tid >> 3);
  const int c0  = (tid & 7) * 32;
  const int q = row >> 6;              // 64-row qtile
  const int a = q >> 3, b = q & 7;
  const int n = a + 1;                 // chunks for this qtile
  const int base = q + 4 * a * (a - 1) + b * a;
  const int lrow = row & 63;

  float M = -3.0e38f;
  for (int i = 0; i < n; i++)
    M = fmaxf(M, ml[(size_t)(base + i) * 128 + lrow * 2]);

  float L = 0.f;
  float acc[32];
  #pragma unroll
  for (int j = 0; j < 32; j++) acc[j] = 0.f;

  for (int i = 0; i < n; i++) {
    const float mi = ml[(size_t)(base + i) * 128 + lrow * 2];
    const float li = ml[(size_t)(base + i) * 128 + lrow * 2 + 1];
    const float fi = __expf(mi - M);
    L += li * fi;
    const unsigned short* src = pOb + (size_t)(base + i) * (64 * 256) + (size_t)lrow * 256 + c0;
    #pragma unroll
    for (int v = 0; v < 4; v++) {
      u16x8 u = *reinterpret_cast<const u16x8*>(src + v * 8);
      #pragma unroll
      for (int j = 0; j < 8; j++) acc[v * 8 + j] += bf2f((unsigned short)u[j]) * fi;
    }
  }
  const float inv = 1.f / L;
  #pragma unroll
  for (int v = 0; v < 8; v++) {
    float4 w;
    w.x = acc[v * 4 + 0] * inv; w.y = acc[v * 4 + 1] * inv;
    w.z = acc[v * 4 + 2] * inv; w.w = acc[v * 4 + 3] * inv;
    *reinterpret_cast<float4*>(&out[(size_t)row * 256 + c0 + v * 4]) = w;
  }
}

extern "C" void kernel_launch(void* const* d_in, const int* in_sizes, int n_in,
                              void* d_out, int out_size, void* d_ws, size_t ws_size,
                              hipStream_t stream)
{
  const float* x  = (const float*)d_in[0];
  const float* Wq = (const float*)d_in[1];
  const float* Wk = (const float*)d_in[2];
  const float* Wv = (const float*)d_in[3];

  char* ws = (char*)d_ws;
  unsigned short* qb  = (unsigned short*)ws;                              // 4 MB
  unsigned short* kb  = (unsigned short*)(ws + (size_t)4  * 1024 * 1024); // 4 MB
  unsigned short* vtb = (unsigned short*)(ws + (size_t)8  * 1024 * 1024); // 4 MB
  float*          ml  = (float*)         (ws + (size_t)12 * 1024 * 1024); // 557 KB
  unsigned short* pOb = (unsigned short*)(ws + (size_t)13 * 1024 * 1024); // 35.7 MB

  proj_kernel<<<dim3(64, 2, 3), 256, 0, stream>>>(x, Wq, Wk, Wv, qb, kb, vtb);
  attn_kernel<<<dim3(NTASKS), 256, 0, stream>>>(qb, kb, vtb, pOb, ml);
  merge_kernel<<<dim3(SEQ / 32), 256, 0, stream>>>(pOb, ml, (float*)d_out);
}